// Round 1
// baseline (1997.880 us; speedup 1.0000x reference)
//
#include <hip/hip_runtime.h>

// ---- problem constants ----
#define SEM_DIM   256
#define CODEBOOK  8192
#define B_        8
#define T_        4096
#define D_        292
#define NCH       37          // 1 sem + 36 ac code channels
#define EPSV      1e-5f

constexpr int ROWS      = B_ * T_;           // 32768
constexpr int CODES_SZ  = B_ * NCH * T_;     // 1,212,416 floats
constexpr int RECON_OFF = CODES_SZ;

// scratch lives inside the recon region of d_out (fully overwritten later)
constexpr int EMB_SZ   = CODEBOOK * SEM_DIM;     // 2,097,152
constexpr int E2_OFF   = EMB_SZ;                 // +8192
constexpr int NSPLIT   = 4;
constexpr int PMIN_OFF = E2_OFF + CODEBOOK;      // +131072
constexpr int PIDX_OFF = PMIN_OFF + ROWS * NSPLIT; // +131072

// ---- kernel 1: emb = es / max(cu,eps); e2 = sum(emb^2) ----
__global__ __launch_bounds__(256) void prep_kernel(
    const float* __restrict__ es, const float* __restrict__ cu,
    float* __restrict__ embw, float* __restrict__ e2)
{
    int c = blockIdx.x;
    int d = threadIdx.x;
    float denom = fmaxf(cu[c], EPSV);
    float v = es[(size_t)c * SEM_DIM + d] / denom;   // IEEE div, matches ref
    embw[(size_t)c * SEM_DIM + d] = v;

    float s = v * v;
    #pragma unroll
    for (int m = 32; m >= 1; m >>= 1) s += __shfl_xor(s, m);
    __shared__ float red[4];
    int lane = threadIdx.x & 63, w = threadIdx.x >> 6;
    if (lane == 0) red[w] = s;
    __syncthreads();
    if (threadIdx.x == 0)
        e2[c] = red[0] + red[1] + red[2] + red[3];
}

// ---- kernel 2: fused GEMM + running argmin over code splits ----
#define BM 64
#define BN 64
#define BK 32
#define LDSP 68   // padded stride (multiple of 4 for aligned float4 reads)

__global__ __launch_bounds__(256) void gemm_argmin_kernel(
    const float* __restrict__ x, const float* __restrict__ embw,
    const float* __restrict__ e2, float* __restrict__ pmin, int* __restrict__ pidx)
{
    __shared__ float a_s[BK][LDSP];
    __shared__ float b_s[BK][LDSP];

    int tid   = threadIdx.x;
    int bm    = blockIdx.x;        // 0..511 : (b, t-chunk)
    int split = blockIdx.y;        // 0..NSPLIT-1
    int b     = bm >> 6;
    int t0    = (bm & 63) * BM;
    int cbase = split * (CODEBOOK / NSPLIT);
    int tx = tid & 15, ty = tid >> 4;

    const float* xbase = x + (size_t)b * D_ * T_ + t0;

    float rm[4];
    int   ri[4];
    #pragma unroll
    for (int i = 0; i < 4; i++) { rm[i] = 3.4e38f; ri[i] = 0; }

    for (int nt = 0; nt < (CODEBOOK / NSPLIT) / BN; ++nt) {
        int c0 = cbase + nt * BN;
        float acc[4][4] = {};

        for (int kt = 0; kt < SEM_DIM / BK; ++kt) {
            int k0 = kt * BK;
            // A tile: a_s[kk][m] = x[b][k0+kk][t0+m]  (64-wide coalesced)
            {
                int m   = tid & 63;
                int kk0 = tid >> 6;
                #pragma unroll
                for (int i = 0; i < 8; i++) {
                    int kk = kk0 + i * 4;
                    a_s[kk][m] = xbase[(size_t)(k0 + kk) * T_ + m];
                }
            }
            // B tile: b_s[kk][n] = emb[c0+n][k0+kk]  (32-wide coalesced)
            {
                int kk = tid & 31;
                int n0 = tid >> 5;
                #pragma unroll
                for (int i = 0; i < 8; i++) {
                    int n = n0 + i * 8;
                    b_s[kk][n] = embw[(size_t)(c0 + n) * SEM_DIM + k0 + kk];
                }
            }
            __syncthreads();
            #pragma unroll
            for (int kk = 0; kk < BK; ++kk) {
                float4 a4 = *(const float4*)(&a_s[kk][ty * 4]);
                float4 b4 = *(const float4*)(&b_s[kk][tx * 4]);
                float av[4] = { a4.x, a4.y, a4.z, a4.w };
                float bv[4] = { b4.x, b4.y, b4.z, b4.w };
                #pragma unroll
                for (int i = 0; i < 4; i++)
                    #pragma unroll
                    for (int j = 0; j < 4; j++)
                        acc[i][j] = fmaf(av[i], bv[j], acc[i][j]);
            }
            __syncthreads();
        }

        // score = e2[c] - 2*dot ; update running argmin (strict < keeps first)
        #pragma unroll
        for (int j = 0; j < 4; j++) {
            int c = c0 + tx * 4 + j;
            float ec = e2[c];
            #pragma unroll
            for (int i = 0; i < 4; i++) {
                float s = ec - 2.0f * acc[i][j];
                if (s < rm[i]) { rm[i] = s; ri[i] = c; }
            }
        }
    }

    // reduce across the 16 lanes (tx) holding the same rows
    #pragma unroll
    for (int i = 0; i < 4; i++) {
        float v = rm[i]; int idx = ri[i];
        #pragma unroll
        for (int m = 1; m < 16; m <<= 1) {
            float ov = __shfl_xor(v, m);
            int   oi = __shfl_xor(idx, m);
            if (ov < v || (ov == v && oi < idx)) { v = ov; idx = oi; }
        }
        if (tx == 0) {
            int r = b * T_ + t0 + ty * 4 + i;
            pmin[r * NSPLIT + split] = v;
            pidx[r * NSPLIT + split] = idx;
        }
    }
}

// ---- kernel 3: merge splits, write sem code (as float) ----
__global__ __launch_bounds__(256) void merge_kernel(
    const float* __restrict__ pmin, const int* __restrict__ pidx,
    float* __restrict__ out)
{
    int r = blockIdx.x * 256 + threadIdx.x;   // 0..32767
    float bv = pmin[r * NSPLIT];
    int   bi = pidx[r * NSPLIT];
    #pragma unroll
    for (int s = 1; s < NSPLIT; s++) {
        float v = pmin[r * NSPLIT + s];
        int   i = pidx[r * NSPLIT + s];
        if (v < bv || (v == bv && i < bi)) { bv = v; bi = i; }
    }
    int b = r >> 12, t = r & 4095;
    out[(size_t)b * NCH * T_ + t] = (float)bi;
}

// ---- kernel 4: FSQ codes + ac recon ----
__global__ __launch_bounds__(256) void fsq_kernel(
    const float* __restrict__ x, float* __restrict__ out)
{
    int e = blockIdx.x * 256 + threadIdx.x;   // < 8*36*4096
    int t = e & 4095;
    int rest = e >> 12;
    int j = rest % 36;
    int b = rest / 36;
    float v = x[(size_t)b * D_ * T_ + (size_t)(SEM_DIM + j) * T_ + t];
    float a = tanhf(v);
    float code = rintf((a + 1.0f) * 10.0f);        // half-even, matches np.round
    out[(size_t)b * NCH * T_ + (size_t)(1 + j) * T_ + t] = code;
    out[RECON_OFF + (size_t)b * D_ * T_ + (size_t)(SEM_DIM + j) * T_ + t]
        = code * 0.1f - 1.0f;
}

// ---- kernel 5: recon sem gather (recomputes emb — bit-identical division) ----
__global__ __launch_bounds__(256) void gather_kernel(
    const float* __restrict__ es, const float* __restrict__ cu,
    const float* __restrict__ codes, float* __restrict__ out)
{
    int bid = blockIdx.x;          // 8 * 64
    int b  = bid >> 6;
    int tc = bid & 63;
    int t  = tc * 64 + (threadIdx.x & 63);
    int w  = threadIdx.x >> 6;     // wave id 0..3 -> d block

    int c = (int)codes[(size_t)b * NCH * T_ + t];
    float denom = fmaxf(cu[c], EPSV);
    const float* erow = es + (size_t)c * SEM_DIM;
    float* orow = out + RECON_OFF + (size_t)b * D_ * T_ + t;

    #pragma unroll
    for (int i = 0; i < 16; i++) {
        int d = w * 64 + i * 4;
        float4 ev = *(const float4*)(erow + d);
        orow[(size_t)(d + 0) * T_] = ev.x / denom;
        orow[(size_t)(d + 1) * T_] = ev.y / denom;
        orow[(size_t)(d + 2) * T_] = ev.z / denom;
        orow[(size_t)(d + 3) * T_] = ev.w / denom;
    }
}

extern "C" void kernel_launch(void* const* d_in, const int* in_sizes, int n_in,
                              void* d_out, int out_size, void* d_ws, size_t ws_size,
                              hipStream_t stream)
{
    const float* x  = (const float*)d_in[0];
    const float* es = (const float*)d_in[1];
    const float* cu = (const float*)d_in[2];
    float* out   = (float*)d_out;
    float* recon = out + RECON_OFF;
    float* embw  = recon;                       // scratch (overwritten later)
    float* e2    = recon + E2_OFF;
    float* pmin  = recon + PMIN_OFF;
    int*   pidx  = (int*)(recon + PIDX_OFF);

    prep_kernel<<<CODEBOOK, 256, 0, stream>>>(es, cu, embw, e2);

    dim3 g(512, NSPLIT);
    gemm_argmin_kernel<<<g, 256, 0, stream>>>(x, embw, e2, pmin, pidx);

    merge_kernel<<<ROWS / 256, 256, 0, stream>>>(pmin, pidx, out);

    fsq_kernel<<<(B_ * 36 * T_) / 256, 256, 0, stream>>>(x, out);

    gather_kernel<<<B_ * (T_ / 64), 256, 0, stream>>>(es, cu, out, out);
}